// Round 1
// baseline (166.460 us; speedup 1.0000x reference)
//
#include <hip/hip_runtime.h>
#include <hip/hip_bf16.h>

typedef unsigned short u16;
typedef __bf16 bf16x8 __attribute__((ext_vector_type(8)));
typedef float f32x4 __attribute__((ext_vector_type(4)));
typedef u16 u16x8 __attribute__((ext_vector_type(8)));
typedef u16 u16x4 __attribute__((ext_vector_type(4)));

__device__ __forceinline__ u16 f2bf(float f) {
    unsigned u = __builtin_bit_cast(unsigned, f);
    unsigned r = u + 0x7FFFu + ((u >> 16) & 1u);
    return (u16)(r >> 16);
}
__device__ __forceinline__ float bf2f(u16 h) {
    return __builtin_bit_cast(float, (unsigned)h << 16);
}

// ---------------- fp32 -> bf16 convert (n multiple of 1024) ----------------
__global__ __launch_bounds__(256) void cvt_bf16(const float* __restrict__ in,
                                                u16* __restrict__ out) {
    int i = (blockIdx.x * 256 + threadIdx.x) * 4;
    float4 v = *(const float4*)(in + i);
    u16x4 o;
    o[0] = f2bf(v.x); o[1] = f2bf(v.y); o[2] = f2bf(v.z); o[3] = f2bf(v.w);
    *(u16x4*)(out + i) = o;
}

// ---------------- bf16 GEMM: C[M][N] = A[M][K] * Bt[N][K]^T ----------------
// 128x128 tile, BK=32, 4 waves (2x2), each wave 64x64 (4x4 frags of 16x16x32)
template <bool OUT_BF16>
__global__ __launch_bounds__(256) void gemm_bt(const u16* __restrict__ A,
                                               const u16* __restrict__ Bt,
                                               void* __restrict__ C,
                                               int M, int N, int K) {
    __shared__ u16 lA[128 * 32];
    __shared__ u16 lB[128 * 32];
    const int tid = threadIdx.x;
    const int lane = tid & 63, wid = tid >> 6;
    const int wm = wid >> 1, wn = wid & 1;
    const int lr = lane & 15, lg = lane >> 4;
    const int bm = blockIdx.x * 128, bn = blockIdx.y * 128;

    f32x4 acc[4][4];
#pragma unroll
    for (int i = 0; i < 4; i++)
#pragma unroll
        for (int j = 0; j < 4; j++) acc[i][j] = (f32x4){0.f, 0.f, 0.f, 0.f};

    const int r0 = tid >> 2;          // 0..63
    const int kp = (tid & 3) * 8;     // 0,8,16,24

    for (int k0 = 0; k0 < K; k0 += 32) {
        u16x8 a0 = *(const u16x8*)(A + (size_t)(bm + r0) * K + k0 + kp);
        u16x8 a1 = *(const u16x8*)(A + (size_t)(bm + r0 + 64) * K + k0 + kp);
        u16x8 b0 = *(const u16x8*)(Bt + (size_t)(bn + r0) * K + k0 + kp);
        u16x8 b1 = *(const u16x8*)(Bt + (size_t)(bn + r0 + 64) * K + k0 + kp);
        __syncthreads();
        *(u16x8*)(lA + r0 * 32 + kp) = a0;
        *(u16x8*)(lA + (r0 + 64) * 32 + kp) = a1;
        *(u16x8*)(lB + r0 * 32 + kp) = b0;
        *(u16x8*)(lB + (r0 + 64) * 32 + kp) = b1;
        __syncthreads();

        bf16x8 af[4], bfr[4];
#pragma unroll
        for (int i = 0; i < 4; i++) {
            af[i]  = *(const bf16x8*)(lA + (wm * 64 + i * 16 + lr) * 32 + lg * 8);
            bfr[i] = *(const bf16x8*)(lB + (wn * 64 + i * 16 + lr) * 32 + lg * 8);
        }
#pragma unroll
        for (int i = 0; i < 4; i++)
#pragma unroll
            for (int j = 0; j < 4; j++)
                acc[i][j] = __builtin_amdgcn_mfma_f32_16x16x32_bf16(af[i], bfr[j],
                                                                    acc[i][j], 0, 0, 0);
    }

    const int row0 = bm + wm * 64, col0 = bn + wn * 64;
#pragma unroll
    for (int i = 0; i < 4; i++)
#pragma unroll
        for (int j = 0; j < 4; j++)
#pragma unroll
            for (int r = 0; r < 4; r++) {
                int m = row0 + i * 16 + lg * 4 + r;
                int n = col0 + j * 16 + lr;
                float v = acc[i][j][r];
                if (OUT_BF16)
                    ((u16*)C)[(size_t)m * N + n] = f2bf(v);
                else
                    ((float*)C)[(size_t)m * N + n] = v;
            }
}

// ---------------- RoPE + RMSNorm on q,k in place (bf16 qkv) ----------------
// one wave per (token, which in {q,k}, head); lane = dim 0..63
__global__ __launch_bounds__(256) void rope_rms(u16* __restrict__ qkv,
                                                const float* __restrict__ cosc,
                                                const float* __restrict__ sinc,
                                                const int* __restrict__ pos_ids) {
    int idx = blockIdx.x * 4 + (threadIdx.x >> 6);
    int lane = threadIdx.x & 63;
    int token = idx >> 5;
    int rem = idx & 31;
    int which = rem >> 4;   // 0=q, 1=k
    int h = rem & 15;
    u16* p = qkv + (size_t)token * 3072 + which * 1024 + h * 64;
    float x = bf2f(p[lane]);
    float xp = __shfl_xor(x, 32);
    int pos = pos_ids[token];
    int j = lane & 31;
    float c = cosc[pos * 32 + j], s = sinc[pos * 32 + j];
    float y = (lane < 32) ? (x * c + xp * s) : (x * c - xp * s);
    float ss = y * y;
#pragma unroll
    for (int m = 1; m < 64; m <<= 1) ss += __shfl_xor(ss, m);
    float r = rsqrtf(ss * (1.0f / 64.0f) + 1.1920929e-07f);
    p[lane] = f2bf(y * r);
}

// ---------------- transpose V: vT[bh][d=64][S] from qkv v slice ----------------
__global__ __launch_bounds__(256) void transpose_v(const u16* __restrict__ qkv,
                                                   u16* __restrict__ vT, int S) {
    int bh = blockIdx.x;
    int b = bh >> 4, h = bh & 15;
    int s0 = blockIdx.y * 64;
    __shared__ u16 lt[64][72];
    int tid = threadIdx.x;
    {
        int s = tid >> 2, dp = (tid & 3) * 16;
        const u16* src = qkv + (size_t)(b * S + s0 + s) * 3072 + 2048 + h * 64 + dp;
        u16x8 v0 = *(const u16x8*)src;
        u16x8 v1 = *(const u16x8*)(src + 8);
#pragma unroll
        for (int i = 0; i < 8; i++) lt[s][dp + i] = v0[i];
#pragma unroll
        for (int i = 0; i < 8; i++) lt[s][dp + 8 + i] = v1[i];
    }
    __syncthreads();
    {
        int d = tid >> 2, sp = (tid & 3) * 16;
        u16x8 o0, o1;
#pragma unroll
        for (int i = 0; i < 8; i++) o0[i] = lt[sp + i][d];
#pragma unroll
        for (int i = 0; i < 8; i++) o1[i] = lt[sp + 8 + i][d];
        u16* dst = vT + ((size_t)bh * 64 + d) * S + s0 + sp;
        *(u16x8*)dst = o0;
        *(u16x8*)(dst + 8) = o1;
    }
}

// ---------------- causal flash attention ----------------
// grid: (B*H, S/64); 4 waves, wave w owns q rows [q0+16w, q0+16w+16)
__global__ __launch_bounds__(256) void attn_fwd(const u16* __restrict__ qkv,
                                                const u16* __restrict__ vT,
                                                u16* __restrict__ out, int S) {
    int bh = blockIdx.x;
    int b = bh >> 4, h = bh & 15;
    int q0 = blockIdx.y * 64;
    int tid = threadIdx.x, lane = tid & 63, w = tid >> 6;
    int q0w = q0 + w * 16;
    const int lr = lane & 15, lg = lane >> 4;

    __shared__ u16 lK[32 * 64];
    __shared__ u16 lV[64 * 32];
    __shared__ u16 lP[4][16 * 32];

    // Q fragments, pre-scaled by 1/sqrt(64)=0.125 (exact in bf16)
    bf16x8 aq[2];
    {
        const u16* qp = qkv + (size_t)(b * S + q0w + lr) * 3072 + h * 64;
#pragma unroll
        for (int hh = 0; hh < 2; hh++) {
            u16x8 t = *(const u16x8*)(qp + hh * 32 + lg * 8);
            bf16x8 a;
#pragma unroll
            for (int i = 0; i < 8; i++) a[i] = (__bf16)(bf2f(t[i]) * 0.125f);
            aq[hh] = a;
        }
    }

    f32x4 oacc[4];
#pragma unroll
    for (int n = 0; n < 4; n++) oacc[n] = (f32x4){0.f, 0.f, 0.f, 0.f};
    float mrow[4] = {-3.0e38f, -3.0e38f, -3.0e38f, -3.0e38f};
    float lsum[4] = {0.f, 0.f, 0.f, 0.f};

    const int kvend = q0 + 64;
    for (int kv0 = 0; kv0 < kvend; kv0 += 32) {
        // stage K tile [32][64] and vT tile [64][32]
        {
            int rr = tid >> 3, dp = (tid & 7) * 8;
            u16x8 kvv = *(const u16x8*)(qkv + (size_t)(b * S + kv0 + rr) * 3072 + 1024 + h * 64 + dp);
            int dd = tid >> 2, sp = (tid & 3) * 8;
            u16x8 vv = *(const u16x8*)(vT + ((size_t)bh * 64 + dd) * S + kv0 + sp);
            __syncthreads();
            *(u16x8*)(lK + rr * 64 + dp) = kvv;
            *(u16x8*)(lV + dd * 32 + sp) = vv;
            __syncthreads();
        }
        if (kv0 <= q0w + 15) {
            // QK^T: 16x32 scores = 2 col-frags x (2 mfma over d halves)
            f32x4 sc[2];
#pragma unroll
            for (int c = 0; c < 2; c++) {
                bf16x8 k0f = *(const bf16x8*)(lK + (c * 16 + lr) * 64 + lg * 8);
                bf16x8 k1f = *(const bf16x8*)(lK + (c * 16 + lr) * 64 + 32 + lg * 8);
                f32x4 z = (f32x4){0.f, 0.f, 0.f, 0.f};
                z = __builtin_amdgcn_mfma_f32_16x16x32_bf16(aq[0], k0f, z, 0, 0, 0);
                sc[c] = __builtin_amdgcn_mfma_f32_16x16x32_bf16(aq[1], k1f, z, 0, 0, 0);
            }
            // mask + online softmax (rows live in 16-lane groups)
#pragma unroll
            for (int r = 0; r < 4; r++) {
                int row = q0w + lg * 4 + r;
#pragma unroll
                for (int c = 0; c < 2; c++) {
                    int col = kv0 + c * 16 + lr;
                    if (col > row) sc[c][r] = -3.0e38f;
                }
                float mx = fmaxf(sc[0][r], sc[1][r]);
#pragma unroll
                for (int msk = 1; msk < 16; msk <<= 1) mx = fmaxf(mx, __shfl_xor(mx, msk));
                float mnew = fmaxf(mrow[r], mx);
                float alpha = __expf(mrow[r] - mnew);
                mrow[r] = mnew;
                float ps = 0.f;
#pragma unroll
                for (int c = 0; c < 2; c++) {
                    float p = __expf(sc[c][r] - mnew);
                    sc[c][r] = p;
                    ps += p;
                }
#pragma unroll
                for (int msk = 1; msk < 16; msk <<= 1) ps += __shfl_xor(ps, msk);
                lsum[r] = lsum[r] * alpha + ps;
#pragma unroll
                for (int n = 0; n < 4; n++) oacc[n][r] *= alpha;
            }
            // P -> LDS (per-wave region), then PV
#pragma unroll
            for (int r = 0; r < 4; r++)
#pragma unroll
                for (int c = 0; c < 2; c++)
                    lP[w][(lg * 4 + r) * 32 + c * 16 + lr] = f2bf(sc[c][r]);
            bf16x8 ap = *(const bf16x8*)(&lP[w][lr * 32 + lg * 8]);
#pragma unroll
            for (int n = 0; n < 4; n++) {
                bf16x8 bv = *(const bf16x8*)(lV + (n * 16 + lr) * 32 + lg * 8);
                oacc[n] = __builtin_amdgcn_mfma_f32_16x16x32_bf16(ap, bv, oacc[n], 0, 0, 0);
            }
        }
    }
    // epilogue: divide by row sum, write bf16 [token][h*64+d]
#pragma unroll
    for (int r = 0; r < 4; r++) {
        int row = q0w + lg * 4 + r;
        float inv = 1.0f / lsum[r];
        size_t base = (size_t)(b * S + row) * 1024 + h * 64;
#pragma unroll
        for (int n = 0; n < 4; n++)
            out[base + n * 16 + lr] = f2bf(oacc[n][r] * inv);
    }
}

extern "C" void kernel_launch(void* const* d_in, const int* in_sizes, int n_in,
                              void* d_out, int out_size, void* d_ws, size_t ws_size,
                              hipStream_t stream) {
    const float* x     = (const float*)d_in[0];
    const float* Wqkv  = (const float*)d_in[1];
    const float* Wo    = (const float*)d_in[2];
    const float* cosc  = (const float*)d_in[3];
    const float* sinc  = (const float*)d_in[4];
    const int* pos_ids = (const int*)d_in[6];

    const int E = 1024, H = 16;
    int S = in_sizes[3] / 32;       // cos_cache is S x 32
    int N = in_sizes[0] / E;
    int B = N / S;

    char* ws = (char*)d_ws;
    u16* xb    = (u16*)ws;                                          // N*E bf16 (reused as attn out)
    u16* wqkvb = (u16*)(ws + (size_t)N * E * 2);                    // 3E*E
    u16* wob   = (u16*)(ws + (size_t)N * E * 2 + (size_t)3 * E * E * 2);
    u16* qkvb  = (u16*)(ws + (size_t)N * E * 2 + (size_t)4 * E * E * 2);
    u16* vTb   = (u16*)(ws + (size_t)N * E * 2 + (size_t)4 * E * E * 2 + (size_t)N * 3 * E * 2);
    u16* aout  = xb;

    cvt_bf16<<<(size_t)N * E / 1024, 256, 0, stream>>>(x, xb);
    cvt_bf16<<<(size_t)3 * E * E / 1024, 256, 0, stream>>>(Wqkv, wqkvb);
    cvt_bf16<<<(size_t)E * E / 1024, 256, 0, stream>>>(Wo, wob);

    gemm_bt<true><<<dim3(N / 128, 3 * E / 128), 256, 0, stream>>>(xb, wqkvb, qkvb, N, 3 * E, E);

    rope_rms<<<N * 2 * H / 4, 256, 0, stream>>>(qkvb, cosc, sinc, pos_ids);

    transpose_v<<<dim3(B * H, S / 64), 256, 0, stream>>>(qkvb, vTb, S);

    attn_fwd<<<dim3(B * H, S / 64), 256, 0, stream>>>(qkvb, vTb, aout, S);

    gemm_bt<false><<<dim3(N / 128, E / 128), 256, 0, stream>>>(aout, wob, d_out, N, E, E);
}

// Round 2
// 141.691 us; speedup vs baseline: 1.1748x; 1.1748x over previous
//
#include <hip/hip_runtime.h>
#include <hip/hip_bf16.h>

typedef unsigned short u16;
typedef __bf16 bf16x8 __attribute__((ext_vector_type(8)));
typedef float f32x4 __attribute__((ext_vector_type(4)));
typedef u16 u16x8 __attribute__((ext_vector_type(8)));
typedef u16 u16x4 __attribute__((ext_vector_type(4)));

__device__ __forceinline__ u16 f2bf(float f) {
    unsigned u = __builtin_bit_cast(unsigned, f);
    unsigned r = u + 0x7FFFu + ((u >> 16) & 1u);
    return (u16)(r >> 16);
}
__device__ __forceinline__ float bf2f(u16 h) {
    return __builtin_bit_cast(float, (unsigned)h << 16);
}
__device__ __forceinline__ unsigned cvt_pk_bf16(float lo, float hi) {
    unsigned r;
    asm("v_cvt_pk_bf16_f32 %0, %1, %2" : "=v"(r) : "v"(lo), "v"(hi));
    return r;
}
__device__ __forceinline__ void gload16(const void* g, void* l) {
    __builtin_amdgcn_global_load_lds((const __attribute__((address_space(1))) void*)g,
                                     (__attribute__((address_space(3))) void*)l, 16, 0, 0);
}

// ---------------- fp32 -> bf16 convert (n multiple of 1024) ----------------
__global__ __launch_bounds__(256) void cvt_bf16(const float* __restrict__ in,
                                                u16* __restrict__ out) {
    int i = (blockIdx.x * 256 + threadIdx.x) * 4;
    float4 v = *(const float4*)(in + i);
    u16x4 o;
    o[0] = f2bf(v.x); o[1] = f2bf(v.y); o[2] = f2bf(v.z); o[3] = f2bf(v.w);
    *(u16x4*)(out + i) = o;
}

// ---------------- bf16 GEMM: C[M][N] = A[M][K] * Bt[N][K]^T ----------------
// 128x128 tile, BK=32, 4 waves (2x2), global_load_lds w=16 staging (m97)
template <bool OUT_BF16>
__global__ __launch_bounds__(256) void gemm_bt(const u16* __restrict__ A,
                                               const u16* __restrict__ Bt,
                                               void* __restrict__ C,
                                               int M, int N, int K) {
    __shared__ u16 lA[128 * 32];
    __shared__ u16 lB[128 * 32];
    const int tid = threadIdx.x;
    const int lane = tid & 63, wid = tid >> 6;
    const int wm = wid >> 1, wn = wid & 1;
    const int lr = lane & 15, lg = lane >> 4;
    const int bm = blockIdx.x * 128, bn = blockIdx.y * 128;
    const int srow = lane >> 2;          // 0..15 row within 16-row chunk
    const int scol = (lane & 3) * 8;     // k-elem offset

    f32x4 acc[4][4];
#pragma unroll
    for (int i = 0; i < 4; i++)
#pragma unroll
        for (int j = 0; j < 4; j++) acc[i][j] = (f32x4){0.f, 0.f, 0.f, 0.f};

    for (int k0 = 0; k0 < K; k0 += 32) {
        __syncthreads();
#pragma unroll
        for (int jj = 0; jj < 2; jj++) {
            int j = wid * 2 + jj;            // chunk: 16 rows x 32 k = 1KB
            int row = j * 16 + srow;
            gload16(A + (size_t)(bm + row) * K + k0 + scol, lA + j * 512);
            gload16(Bt + (size_t)(bn + row) * K + k0 + scol, lB + j * 512);
        }
        __syncthreads();

        bf16x8 af[4], bfr[4];
#pragma unroll
        for (int i = 0; i < 4; i++) {
            af[i]  = *(const bf16x8*)(lA + (wm * 64 + i * 16 + lr) * 32 + lg * 8);
            bfr[i] = *(const bf16x8*)(lB + (wn * 64 + i * 16 + lr) * 32 + lg * 8);
        }
#pragma unroll
        for (int i = 0; i < 4; i++)
#pragma unroll
            for (int j = 0; j < 4; j++)
                acc[i][j] = __builtin_amdgcn_mfma_f32_16x16x32_bf16(af[i], bfr[j],
                                                                    acc[i][j], 0, 0, 0);
    }

    const int row0 = bm + wm * 64, col0 = bn + wn * 64;
#pragma unroll
    for (int i = 0; i < 4; i++)
#pragma unroll
        for (int j = 0; j < 4; j++)
#pragma unroll
            for (int r = 0; r < 4; r++) {
                int m = row0 + i * 16 + lg * 4 + r;
                int n = col0 + j * 16 + lr;
                float v = acc[i][j][r];
                if (OUT_BF16)
                    ((u16*)C)[(size_t)m * N + n] = f2bf(v);
                else
                    ((float*)C)[(size_t)m * N + n] = v;
            }
}

// ---------------- RoPE + RMSNorm on q,k in place (bf16 qkv) ----------------
__global__ __launch_bounds__(256) void rope_rms(u16* __restrict__ qkv,
                                                const float* __restrict__ cosc,
                                                const float* __restrict__ sinc,
                                                const int* __restrict__ pos_ids) {
    int idx = blockIdx.x * 4 + (threadIdx.x >> 6);
    int lane = threadIdx.x & 63;
    int token = idx >> 5;
    int rem = idx & 31;
    int which = rem >> 4;   // 0=q, 1=k
    int h = rem & 15;
    u16* p = qkv + (size_t)token * 3072 + which * 1024 + h * 64;
    float x = bf2f(p[lane]);
    float xp = __shfl_xor(x, 32);
    int pos = pos_ids[token];
    int j = lane & 31;
    float c = cosc[pos * 32 + j], s = sinc[pos * 32 + j];
    float y = (lane < 32) ? (x * c + xp * s) : (x * c - xp * s);
    float ss = y * y;
#pragma unroll
    for (int m = 1; m < 64; m <<= 1) ss += __shfl_xor(ss, m);
    float r = rsqrtf(ss * (1.0f / 64.0f) + 1.1920929e-07f);
    p[lane] = f2bf(y * r);
}

// ---------------- transpose V: vT[bh][d=64][S] ----------------
__global__ __launch_bounds__(256) void transpose_v(const u16* __restrict__ qkv,
                                                   u16* __restrict__ vT, int S) {
    int bh = blockIdx.x;
    int b = bh >> 4, h = bh & 15;
    int s0 = blockIdx.y * 64;
    __shared__ u16 lt[64][72];
    int tid = threadIdx.x;
    {
        int s = tid >> 2, dp = (tid & 3) * 16;
        const u16* src = qkv + (size_t)(b * S + s0 + s) * 3072 + 2048 + h * 64 + dp;
        u16x8 v0 = *(const u16x8*)src;
        u16x8 v1 = *(const u16x8*)(src + 8);
#pragma unroll
        for (int i = 0; i < 8; i++) lt[s][dp + i] = v0[i];
#pragma unroll
        for (int i = 0; i < 8; i++) lt[s][dp + 8 + i] = v1[i];
    }
    __syncthreads();
    {
        int d = tid >> 2, sp = (tid & 3) * 16;
        u16x8 o0, o1;
#pragma unroll
        for (int i = 0; i < 8; i++) o0[i] = lt[sp + i][d];
#pragma unroll
        for (int i = 0; i < 8; i++) o1[i] = lt[sp + 8 + i][d];
        u16* dst = vT + ((size_t)bh * 64 + d) * S + s0 + sp;
        *(u16x8*)dst = o0;
        *(u16x8*)(dst + 8) = o1;
    }
}

// ---------------- causal flash attention, swapped-operand form ----------------
// grid (B*H, S/128); 4 waves; wave w owns q rows [q0+32w, q0+32w+32) as 2 frags.
// S^T = mfma(Kfrag, Qfrag): lane holds S^T[kv=kf*16+lg*4+r][q=lr] -> lane-local
// softmax per q column (2 shuffles per 64 kv). O accumulated as O^T (col=q=lr).
__global__ __launch_bounds__(256) void attn_fwd(const u16* __restrict__ qkv,
                                                const u16* __restrict__ vT,
                                                u16* __restrict__ out, int S) {
    const int bh = blockIdx.x, b = bh >> 4, h = bh & 15;
    const int q0 = blockIdx.y * 128;
    const int tid = threadIdx.x, lane = tid & 63, w = tid >> 6;
    const int lr = lane & 15, lg = lane >> 4;
    const int q0w = q0 + w * 32;
    const int sw = (lr & 7) << 4;            // read-side XOR swizzle (byte)

    __shared__ u16 lK[64 * 64];              // [kv][d], rows 128B, swizzled
    __shared__ u16 lVt[64 * 64];             // [d][kv], rows 128B, swizzled
    __shared__ u16 lP[4][2][16 * 64];        // per wave/qh: P[q][k], swizzled

    // Q fragments (standard A-layout == B-operand for swapped QK^T), x0.125
    bf16x8 bQ[2][2];
#pragma unroll
    for (int qh = 0; qh < 2; qh++) {
        const u16* qp = qkv + (size_t)(b * S + q0w + qh * 16 + lr) * 3072 + h * 64;
#pragma unroll
        for (int hf = 0; hf < 2; hf++) {
            u16x8 t = *(const u16x8*)(qp + hf * 32 + lg * 8);
            bf16x8 a;
#pragma unroll
            for (int i = 0; i < 8; i++) a[i] = (__bf16)(bf2f(t[i]) * 0.125f);
            bQ[qh][hf] = a;
        }
    }

    f32x4 oT[2][4];                          // O^T: row d=df*16+lg*4+r, col q=lr
#pragma unroll
    for (int qh = 0; qh < 2; qh++)
#pragma unroll
        for (int df = 0; df < 4; df++) oT[qh][df] = (f32x4){0.f, 0.f, 0.f, 0.f};
    float mrun[2] = {-3.0e38f, -3.0e38f}, lrun[2] = {0.f, 0.f};

    const int jrow = lane >> 3;              // staging: row within 8-row chunk
    const int cb = (lane & 7) * 16;          // staging: byte col
    const int kvend = q0 + 128;

    for (int kv0 = 0; kv0 < kvend; kv0 += 64) {
        __syncthreads();
#pragma unroll
        for (int jj = 0; jj < 2; jj++) {
            int j = w * 2 + jj;              // chunk: 8 rows x 128B = 1KB
            int row = j * 8 + jrow;
            int scb = cb ^ ((row & 7) << 4); // pre-swizzled source col (rule 21)
            gload16(qkv + (size_t)(b * S + kv0 + row) * 3072 + 1024 + h * 64 + (scb >> 1),
                    lK + j * 512);
            gload16(vT + ((size_t)bh * 64 + row) * S + kv0 + (scb >> 1),
                    lVt + j * 512);
        }
        __syncthreads();
        if (kv0 > q0w + 31) continue;        // wave fully masked this step
        const bool a0 = (kv0 <= q0w + 15);   // qh=0 active?

        // ---- QK^T (swapped): S^T[kv][q] ----
        f32x4 st[2][4];
#pragma unroll
        for (int kf = 0; kf < 4; kf++) {
            const char* kb = (const char*)lK + (kf * 16 + lr) * 128;
            bf16x8 k0 = *(const bf16x8*)(kb + ((lg * 16) ^ sw));
            bf16x8 k1 = *(const bf16x8*)(kb + ((64 + lg * 16) ^ sw));
            f32x4 z0 = (f32x4){0.f, 0.f, 0.f, 0.f};
            if (a0) {
                f32x4 z = __builtin_amdgcn_mfma_f32_16x16x32_bf16(k0, bQ[0][0], z0, 0, 0, 0);
                st[0][kf] = __builtin_amdgcn_mfma_f32_16x16x32_bf16(k1, bQ[0][1], z, 0, 0, 0);
            }
            {
                f32x4 z = __builtin_amdgcn_mfma_f32_16x16x32_bf16(k0, bQ[1][0], z0, 0, 0, 0);
                st[1][kf] = __builtin_amdgcn_mfma_f32_16x16x32_bf16(k1, bQ[1][1], z, 0, 0, 0);
            }
        }

        // ---- mask + lane-local online softmax + P store ----
#pragma unroll
        for (int qh = 0; qh < 2; qh++) {
            if (qh == 0 && !a0) continue;
            const int qg = q0w + qh * 16 + lr;
            float mx = -3.0e38f;
#pragma unroll
            for (int kf = 0; kf < 4; kf++)
#pragma unroll
                for (int r = 0; r < 4; r++) {
                    int kvg = kv0 + kf * 16 + lg * 4 + r;
                    float v = (kvg > qg) ? -3.0e38f : st[qh][kf][r];
                    st[qh][kf][r] = v;
                    mx = fmaxf(mx, v);
                }
            mx = fmaxf(mx, __shfl_xor(mx, 16));
            mx = fmaxf(mx, __shfl_xor(mx, 32));
            float mnew = fmaxf(mrun[qh], mx);
            float alpha = __expf(mrun[qh] - mnew);
            mrun[qh] = mnew;
            float ps = 0.f;
#pragma unroll
            for (int kf = 0; kf < 4; kf++)
#pragma unroll
                for (int r = 0; r < 4; r++) {
                    float p = __expf(st[qh][kf][r] - mnew);
                    st[qh][kf][r] = p;
                    ps += p;
                }
            ps += __shfl_xor(ps, 16);
            ps += __shfl_xor(ps, 32);
            lrun[qh] = lrun[qh] * alpha + ps;
#pragma unroll
            for (int df = 0; df < 4; df++)
#pragma unroll
                for (int r = 0; r < 4; r++) oT[qh][df][r] *= alpha;
            // store P[q=lr][k] packed bf16, swizzled by row (=lr)
            char* pb = (char*)&lP[w][qh][0] + lr * 128;
#pragma unroll
            for (int kf = 0; kf < 4; kf++) {
                uint2 pk;
                pk.x = cvt_pk_bf16(st[qh][kf][0], st[qh][kf][1]);
                pk.y = cvt_pk_bf16(st[qh][kf][2], st[qh][kf][3]);
                *(uint2*)(pb + ((kf * 32 + lg * 8) ^ sw)) = pk;
            }
        }

        // ---- PV (swapped): O^T += Vt . P^T ----
#pragma unroll
        for (int kc = 0; kc < 2; kc++) {
            bf16x8 bp[2];
#pragma unroll
            for (int qh = 0; qh < 2; qh++)
                bp[qh] = *(const bf16x8*)((const char*)&lP[w][qh][0] + lr * 128 +
                                          ((kc * 64 + lg * 16) ^ sw));
#pragma unroll
            for (int df = 0; df < 4; df++) {
                bf16x8 av = *(const bf16x8*)((const char*)lVt + (df * 16 + lr) * 128 +
                                             ((kc * 64 + lg * 16) ^ sw));
                if (a0)
                    oT[0][df] = __builtin_amdgcn_mfma_f32_16x16x32_bf16(av, bp[0], oT[0][df], 0, 0, 0);
                oT[1][df] = __builtin_amdgcn_mfma_f32_16x16x32_bf16(av, bp[1], oT[1][df], 0, 0, 0);
            }
        }
    }

    // epilogue: O^T lane holds q=lr, d=df*16+lg*4+r (4 consecutive d -> b64 store)
#pragma unroll
    for (int qh = 0; qh < 2; qh++) {
        float inv = 1.0f / lrun[qh];
        u16* op = out + (size_t)(b * S + q0w + qh * 16 + lr) * 1024 + h * 64 + lg * 4;
#pragma unroll
        for (int df = 0; df < 4; df++) {
            u16x4 o;
#pragma unroll
            for (int r = 0; r < 4; r++) o[r] = f2bf(oT[qh][df][r] * inv);
            *(u16x4*)(op + df * 16) = o;
        }
    }
}

extern "C" void kernel_launch(void* const* d_in, const int* in_sizes, int n_in,
                              void* d_out, int out_size, void* d_ws, size_t ws_size,
                              hipStream_t stream) {
    const float* x     = (const float*)d_in[0];
    const float* Wqkv  = (const float*)d_in[1];
    const float* Wo    = (const float*)d_in[2];
    const float* cosc  = (const float*)d_in[3];
    const float* sinc  = (const float*)d_in[4];
    const int* pos_ids = (const int*)d_in[6];

    const int E = 1024, H = 16;
    int S = in_sizes[3] / 32;       // cos_cache is S x 32
    int N = in_sizes[0] / E;
    int B = N / S;

    char* ws = (char*)d_ws;
    u16* xb    = (u16*)ws;                                          // N*E bf16 (reused as attn out)
    u16* wqkvb = (u16*)(ws + (size_t)N * E * 2);                    // 3E*E
    u16* wob   = (u16*)(ws + (size_t)N * E * 2 + (size_t)3 * E * E * 2);
    u16* qkvb  = (u16*)(ws + (size_t)N * E * 2 + (size_t)4 * E * E * 2);
    u16* vTb   = (u16*)(ws + (size_t)N * E * 2 + (size_t)4 * E * E * 2 + (size_t)N * 3 * E * 2);
    u16* aout  = xb;

    cvt_bf16<<<(size_t)N * E / 1024, 256, 0, stream>>>(x, xb);
    cvt_bf16<<<(size_t)3 * E * E / 1024, 256, 0, stream>>>(Wqkv, wqkvb);
    cvt_bf16<<<(size_t)E * E / 1024, 256, 0, stream>>>(Wo, wob);

    gemm_bt<true><<<dim3(N / 128, 3 * E / 128), 256, 0, stream>>>(xb, wqkvb, qkvb, N, 3 * E, E);

    rope_rms<<<N * 2 * H / 4, 256, 0, stream>>>(qkvb, cosc, sinc, pos_ids);

    transpose_v<<<dim3(B * H, S / 64), 256, 0, stream>>>(qkvb, vTb, S);

    attn_fwd<<<dim3(B * H, S / 128), 256, 0, stream>>>(qkvb, vTb, aout, S);

    gemm_bt<false><<<dim3(N / 128, E / 128), 256, 0, stream>>>(aout, wob, d_out, N, E, E);
}

// Round 3
// 129.871 us; speedup vs baseline: 1.2817x; 1.0910x over previous
//
#include <hip/hip_runtime.h>
#include <hip/hip_bf16.h>

typedef unsigned short u16;
typedef __bf16 bf16x8 __attribute__((ext_vector_type(8)));
typedef float f32x4 __attribute__((ext_vector_type(4)));
typedef u16 u16x8 __attribute__((ext_vector_type(8)));
typedef u16 u16x4 __attribute__((ext_vector_type(4)));

__device__ __forceinline__ u16 f2bf(float f) {
    unsigned u = __builtin_bit_cast(unsigned, f);
    unsigned r = u + 0x7FFFu + ((u >> 16) & 1u);
    return (u16)(r >> 16);
}
__device__ __forceinline__ float bf2f(u16 h) {
    return __builtin_bit_cast(float, (unsigned)h << 16);
}
__device__ __forceinline__ unsigned cvt_pk_bf16(float lo, float hi) {
    unsigned r;
    asm("v_cvt_pk_bf16_f32 %0, %1, %2" : "=v"(r) : "v"(lo), "v"(hi));
    return r;
}
__device__ __forceinline__ void gload16(const void* g, void* l) {
    __builtin_amdgcn_global_load_lds((const __attribute__((address_space(1))) void*)g,
                                     (__attribute__((address_space(3))) void*)l, 16, 0, 0);
}

// ---------------- fp32 -> bf16 convert (n multiple of 1024) ----------------
__global__ __launch_bounds__(256) void cvt_bf16(const float* __restrict__ in,
                                                u16* __restrict__ out) {
    int i = (blockIdx.x * 256 + threadIdx.x) * 4;
    float4 v = *(const float4*)(in + i);
    u16x4 o;
    o[0] = f2bf(v.x); o[1] = f2bf(v.y); o[2] = f2bf(v.z); o[3] = f2bf(v.w);
    *(u16x4*)(out + i) = o;
}

// ---------------- bf16 GEMM: C[M][N] = A[M][K] * Bt[N][K]^T ----------------
// 128x128 tile, BK=32, 4 waves (2x2), global_load_lds w=16 staging (m97)
template <bool OUT_BF16>
__global__ __launch_bounds__(256) void gemm_bt(const u16* __restrict__ A,
                                               const u16* __restrict__ Bt,
                                               void* __restrict__ C,
                                               int M, int N, int K) {
    __shared__ u16 lA[128 * 32];
    __shared__ u16 lB[128 * 32];
    const int tid = threadIdx.x;
    const int lane = tid & 63, wid = tid >> 6;
    const int wm = wid >> 1, wn = wid & 1;
    const int lr = lane & 15, lg = lane >> 4;
    const int bm = blockIdx.x * 128, bn = blockIdx.y * 128;
    const int srow = lane >> 2;          // 0..15 row within 16-row chunk
    const int scol = (lane & 3) * 8;     // k-elem offset

    f32x4 acc[4][4];
#pragma unroll
    for (int i = 0; i < 4; i++)
#pragma unroll
        for (int j = 0; j < 4; j++) acc[i][j] = (f32x4){0.f, 0.f, 0.f, 0.f};

    for (int k0 = 0; k0 < K; k0 += 32) {
        __syncthreads();
#pragma unroll
        for (int jj = 0; jj < 2; jj++) {
            int j = wid * 2 + jj;            // chunk: 16 rows x 32 k = 1KB
            int row = j * 16 + srow;
            gload16(A + (size_t)(bm + row) * K + k0 + scol, lA + j * 512);
            gload16(Bt + (size_t)(bn + row) * K + k0 + scol, lB + j * 512);
        }
        __syncthreads();

        bf16x8 af[4], bfr[4];
#pragma unroll
        for (int i = 0; i < 4; i++) {
            af[i]  = *(const bf16x8*)(lA + (wm * 64 + i * 16 + lr) * 32 + lg * 8);
            bfr[i] = *(const bf16x8*)(lB + (wn * 64 + i * 16 + lr) * 32 + lg * 8);
        }
#pragma unroll
        for (int i = 0; i < 4; i++)
#pragma unroll
            for (int j = 0; j < 4; j++)
                acc[i][j] = __builtin_amdgcn_mfma_f32_16x16x32_bf16(af[i], bfr[j],
                                                                    acc[i][j], 0, 0, 0);
    }

    const int row0 = bm + wm * 64, col0 = bn + wn * 64;
#pragma unroll
    for (int i = 0; i < 4; i++)
#pragma unroll
        for (int j = 0; j < 4; j++)
#pragma unroll
            for (int r = 0; r < 4; r++) {
                int m = row0 + i * 16 + lg * 4 + r;
                int n = col0 + j * 16 + lr;
                float v = acc[i][j][r];
                if (OUT_BF16)
                    ((u16*)C)[(size_t)m * N + n] = f2bf(v);
                else
                    ((float*)C)[(size_t)m * N + n] = v;
            }
}

// ---------------- RoPE + RMSNorm on q,k in place (bf16 qkv) ----------------
__global__ __launch_bounds__(256) void rope_rms(u16* __restrict__ qkv,
                                                const float* __restrict__ cosc,
                                                const float* __restrict__ sinc,
                                                const int* __restrict__ pos_ids) {
    int idx = blockIdx.x * 4 + (threadIdx.x >> 6);
    int lane = threadIdx.x & 63;
    int token = idx >> 5;
    int rem = idx & 31;
    int which = rem >> 4;   // 0=q, 1=k
    int h = rem & 15;
    u16* p = qkv + (size_t)token * 3072 + which * 1024 + h * 64;
    float x = bf2f(p[lane]);
    float xp = __shfl_xor(x, 32);
    int pos = pos_ids[token];
    int j = lane & 31;
    float c = cosc[pos * 32 + j], s = sinc[pos * 32 + j];
    float y = (lane < 32) ? (x * c + xp * s) : (x * c - xp * s);
    float ss = y * y;
#pragma unroll
    for (int m = 1; m < 64; m <<= 1) ss += __shfl_xor(ss, m);
    float r = rsqrtf(ss * (1.0f / 64.0f) + 1.1920929e-07f);
    p[lane] = f2bf(y * r);
}

// ---------------- transpose V: vT[bh][d=64][S] ----------------
__global__ __launch_bounds__(256) void transpose_v(const u16* __restrict__ qkv,
                                                   u16* __restrict__ vT, int S) {
    int bh = blockIdx.x;
    int b = bh >> 4, h = bh & 15;
    int s0 = blockIdx.y * 64;
    __shared__ u16 lt[64][72];
    int tid = threadIdx.x;
    {
        int s = tid >> 2, dp = (tid & 3) * 16;
        const u16* src = qkv + (size_t)(b * S + s0 + s) * 3072 + 2048 + h * 64 + dp;
        u16x8 v0 = *(const u16x8*)src;
        u16x8 v1 = *(const u16x8*)(src + 8);
#pragma unroll
        for (int i = 0; i < 8; i++) lt[s][dp + i] = v0[i];
#pragma unroll
        for (int i = 0; i < 8; i++) lt[s][dp + 8 + i] = v1[i];
    }
    __syncthreads();
    {
        int d = tid >> 2, sp = (tid & 3) * 16;
        u16x8 o0, o1;
#pragma unroll
        for (int i = 0; i < 8; i++) o0[i] = lt[sp + i][d];
#pragma unroll
        for (int i = 0; i < 8; i++) o1[i] = lt[sp + 8 + i][d];
        u16* dst = vT + ((size_t)bh * 64 + d) * S + s0 + sp;
        *(u16x8*)dst = o0;
        *(u16x8*)(dst + 8) = o1;
    }
}

// ---------------- causal flash attention, balanced-pair + dbuf ----------------
// grid (B*H, S/128). Block p handles q-tiles {p, nq-1-p} (nq = S/64) sequentially
// -> every block does exactly nq+1 kv-steps (balanced). 4 waves, wave w owns
// q rows [tile*64 + 16w, +16). Swapped QK^T: lane holds S^T[kv][q=lr], softmax
// lane-local (2 shuffles). K/V LDS double-buffered, one barrier per step (T3-min).
__global__ __launch_bounds__(256) void attn_fwd(const u16* __restrict__ qkv,
                                                const u16* __restrict__ vT,
                                                u16* __restrict__ out, int S) {
    const int bh = blockIdx.x, b = bh >> 4, h = bh & 15;
    const int tid = threadIdx.x, lane = tid & 63, w = tid >> 6;
    const int lr = lane & 15, lg = lane >> 4;
    const int sw = (lr & 7) << 4;            // read-side XOR swizzle (byte)

    const int nq = S >> 6;
    const int i1 = blockIdx.y;               // light tile
    const int i2 = (nq - 1) - i1;            // heavy tile
    const int n1 = i1 + 1, ntot = n1 + i2 + 1;

    __shared__ u16 lK[2][64 * 64];           // [kv][d], rows 128B, swizzled
    __shared__ u16 lVt[2][64 * 64];          // [d][kv], rows 128B, swizzled
    __shared__ u16 lP[4][16 * 64];           // per wave: P[q][k], swizzled

    // staging geometry: 8 chunks of 8 rows x 128B; wave w owns chunks 2w, 2w+1
    const int jr = lane >> 3;                // row within chunk
    const int cbyte = (lane & 7) * 16;
    const int scb = cbyte ^ (jr << 4);       // pre-swizzled source byte col
    const int rowA = w * 16 + jr, rowB = rowA + 8;
    const u16* kSrc = qkv + 1024 + h * 64 + (scb >> 1);
    const u16* vSrc = vT + (size_t)bh * 64 * S + (scb >> 1);

#define STAGE(bufi, kv0_)                                                        \
    {                                                                            \
        const u16* kb = kSrc + (size_t)(b * S + (kv0_)) * 3072;                  \
        const u16* vb = vSrc + (kv0_);                                           \
        gload16(kb + (size_t)rowA * 3072, &lK[bufi][(w * 2) * 512]);             \
        gload16(kb + (size_t)rowB * 3072, &lK[bufi][(w * 2 + 1) * 512]);         \
        gload16(vb + (size_t)rowA * S, &lVt[bufi][(w * 2) * 512]);               \
        gload16(vb + (size_t)rowB * S, &lVt[bufi][(w * 2 + 1) * 512]);           \
    }

    bf16x8 bQ[2];
    f32x4 oT[4];
    float mrun, lrun;

#define LOADQ(tile_)                                                             \
    {                                                                            \
        const u16* qp = qkv + (size_t)(b * S + (tile_)*64 + w * 16 + lr) * 3072 + h * 64; \
        _Pragma("unroll") for (int hf = 0; hf < 2; hf++) {                       \
            u16x8 t = *(const u16x8*)(qp + hf * 32 + lg * 8);                    \
            bf16x8 a;                                                            \
            _Pragma("unroll") for (int i = 0; i < 8; i++)                        \
                a[i] = (__bf16)(bf2f(t[i]) * 0.125f);                            \
            bQ[hf] = a;                                                          \
        }                                                                        \
    }

    STAGE(0, 0);
    LOADQ(i1);
#pragma unroll
    for (int df = 0; df < 4; df++) oT[df] = (f32x4){0.f, 0.f, 0.f, 0.f};
    mrun = -3.0e38f; lrun = 0.f;
    __syncthreads();

    int buf = 0;
    for (int s = 0; s < ntot; s++) {
        const int tile = (s < n1) ? i1 : i2;
        const int kv0 = ((s < n1) ? s : s - n1) * 64;
        if (s + 1 < ntot) {
            int ns = s + 1;
            int nkv0 = ((ns < n1) ? ns : ns - n1) * 64;
            STAGE(buf ^ 1, nkv0);
        }
        const bool diag = (s == n1 - 1) || (s == ntot - 1);

        // ---- QK^T (swapped): S^T[kv][q] ----
        f32x4 st[4];
#pragma unroll
        for (int kf = 0; kf < 4; kf++) {
            const char* kb = (const char*)&lK[buf][0] + (kf * 16 + lr) * 128;
            bf16x8 k0 = *(const bf16x8*)(kb + ((lg * 16) ^ sw));
            bf16x8 k1 = *(const bf16x8*)(kb + ((64 + lg * 16) ^ sw));
            f32x4 z = (f32x4){0.f, 0.f, 0.f, 0.f};
            z = __builtin_amdgcn_mfma_f32_16x16x32_bf16(k0, bQ[0], z, 0, 0, 0);
            st[kf] = __builtin_amdgcn_mfma_f32_16x16x32_bf16(k1, bQ[1], z, 0, 0, 0);
        }

        // ---- mask (diagonal steps only) + lane-local online softmax ----
        if (diag) {
            const int qg = tile * 64 + w * 16 + lr;
#pragma unroll
            for (int kf = 0; kf < 4; kf++)
#pragma unroll
                for (int r = 0; r < 4; r++) {
                    int kvg = kv0 + kf * 16 + lg * 4 + r;
                    if (kvg > qg) st[kf][r] = -3.0e38f;
                }
        }
        float mx = -3.0e38f;
#pragma unroll
        for (int kf = 0; kf < 4; kf++) {
            float m01 = fmaxf(st[kf][0], st[kf][1]);
            float m23 = fmaxf(st[kf][2], st[kf][3]);
            mx = fmaxf(mx, fmaxf(m01, m23));
        }
        mx = fmaxf(mx, __shfl_xor(mx, 16));
        mx = fmaxf(mx, __shfl_xor(mx, 32));
        if (!__all(mx <= mrun + 8.f)) {       // T13 defer-max
            float mnew = fmaxf(mrun, mx);
            float alpha = __expf(mrun - mnew);
            mrun = mnew;
            lrun *= alpha;
#pragma unroll
            for (int df = 0; df < 4; df++)
#pragma unroll
                for (int r = 0; r < 4; r++) oT[df][r] *= alpha;
        }
        float ps = 0.f;
#pragma unroll
        for (int kf = 0; kf < 4; kf++)
#pragma unroll
            for (int r = 0; r < 4; r++) {
                float p = __expf(st[kf][r] - mrun);
                st[kf][r] = p;
                ps += p;
            }
        ps += __shfl_xor(ps, 16);
        ps += __shfl_xor(ps, 32);
        lrun += ps;

        // ---- P -> LDS (bf16, swizzled rows of 128B) ----
        {
            char* pb = (char*)&lP[w][0] + lr * 128;
#pragma unroll
            for (int kf = 0; kf < 4; kf++) {
                uint2 pk;
                pk.x = cvt_pk_bf16(st[kf][0], st[kf][1]);
                pk.y = cvt_pk_bf16(st[kf][2], st[kf][3]);
                *(uint2*)(pb + ((kf * 32 + lg * 8) ^ sw)) = pk;
            }
        }

        // ---- PV (swapped): O^T += Vt . P^T ----
#pragma unroll
        for (int kc = 0; kc < 2; kc++) {
            bf16x8 bp = *(const bf16x8*)((const char*)&lP[w][0] + lr * 128 +
                                         ((kc * 64 + lg * 16) ^ sw));
#pragma unroll
            for (int df = 0; df < 4; df++) {
                bf16x8 av = *(const bf16x8*)((const char*)&lVt[buf][0] +
                                             (df * 16 + lr) * 128 +
                                             ((kc * 64 + lg * 16) ^ sw));
                oT[df] = __builtin_amdgcn_mfma_f32_16x16x32_bf16(av, bp, oT[df], 0, 0, 0);
            }
        }

        if (diag) {
            // epilogue for this tile: lane holds q=lr, d=df*16+lg*4+r
            float inv = 1.0f / lrun;
            u16* op = out + (size_t)(b * S + tile * 64 + w * 16 + lr) * 1024 +
                      h * 64 + lg * 4;
#pragma unroll
            for (int df = 0; df < 4; df++) {
                u16x4 o;
#pragma unroll
                for (int r = 0; r < 4; r++) o[r] = f2bf(oT[df][r] * inv);
                *(u16x4*)(op + df * 16) = o;
            }
            if (s != ntot - 1) {              // switch to heavy tile
                LOADQ(i2);
#pragma unroll
                for (int df = 0; df < 4; df++) oT[df] = (f32x4){0.f, 0.f, 0.f, 0.f};
                mrun = -3.0e38f; lrun = 0.f;
            }
        }
        __syncthreads();                      // vmcnt(0)+lgkmcnt(0)+barrier
        buf ^= 1;
    }
#undef STAGE
#undef LOADQ
}

extern "C" void kernel_launch(void* const* d_in, const int* in_sizes, int n_in,
                              void* d_out, int out_size, void* d_ws, size_t ws_size,
                              hipStream_t stream) {
    const float* x     = (const float*)d_in[0];
    const float* Wqkv  = (const float*)d_in[1];
    const float* Wo    = (const float*)d_in[2];
    const float* cosc  = (const float*)d_in[3];
    const float* sinc  = (const float*)d_in[4];
    const int* pos_ids = (const int*)d_in[6];

    const int E = 1024, H = 16;
    int S = in_sizes[3] / 32;       // cos_cache is S x 32
    int N = in_sizes[0] / E;
    int B = N / S;

    char* ws = (char*)d_ws;
    u16* xb    = (u16*)ws;                                          // N*E bf16 (reused as attn out)
    u16* wqkvb = (u16*)(ws + (size_t)N * E * 2);                    // 3E*E
    u16* wob   = (u16*)(ws + (size_t)N * E * 2 + (size_t)3 * E * E * 2);
    u16* qkvb  = (u16*)(ws + (size_t)N * E * 2 + (size_t)4 * E * E * 2);
    u16* vTb   = (u16*)(ws + (size_t)N * E * 2 + (size_t)4 * E * E * 2 + (size_t)N * 3 * E * 2);
    u16* aout  = xb;

    cvt_bf16<<<(size_t)N * E / 1024, 256, 0, stream>>>(x, xb);
    cvt_bf16<<<(size_t)3 * E * E / 1024, 256, 0, stream>>>(Wqkv, wqkvb);
    cvt_bf16<<<(size_t)E * E / 1024, 256, 0, stream>>>(Wo, wob);

    gemm_bt<true><<<dim3(N / 128, 3 * E / 128), 256, 0, stream>>>(xb, wqkvb, qkvb, N, 3 * E, E);

    rope_rms<<<N * 2 * H / 4, 256, 0, stream>>>(qkvb, cosc, sinc, pos_ids);

    transpose_v<<<dim3(B * H, S / 64), 256, 0, stream>>>(qkvb, vTb, S);

    attn_fwd<<<dim3(B * H, S / 128), 256, 0, stream>>>(qkvb, vTb, aout, S);

    gemm_bt<false><<<dim3(N / 128, E / 128), 256, 0, stream>>>(aout, wob, d_out, N, E, E);
}

// Round 4
// 120.684 us; speedup vs baseline: 1.3793x; 1.0761x over previous
//
#include <hip/hip_runtime.h>
#include <hip/hip_bf16.h>

typedef unsigned short u16;
typedef __bf16 bf16x8 __attribute__((ext_vector_type(8)));
typedef float f32x4 __attribute__((ext_vector_type(4)));
typedef u16 u16x8 __attribute__((ext_vector_type(8)));
typedef u16 u16x4 __attribute__((ext_vector_type(4)));

__device__ __forceinline__ u16 f2bf(float f) {
    unsigned u = __builtin_bit_cast(unsigned, f);
    unsigned r = u + 0x7FFFu + ((u >> 16) & 1u);
    return (u16)(r >> 16);
}
__device__ __forceinline__ float bf2f(u16 h) {
    return __builtin_bit_cast(float, (unsigned)h << 16);
}
__device__ __forceinline__ unsigned cvt_pk_bf16(float lo, float hi) {
    unsigned r;
    asm("v_cvt_pk_bf16_f32 %0, %1, %2" : "=v"(r) : "v"(lo), "v"(hi));
    return r;
}
__device__ __forceinline__ void gload16(const void* g, void* l) {
    __builtin_amdgcn_global_load_lds((const __attribute__((address_space(1))) void*)g,
                                     (__attribute__((address_space(3))) void*)l, 16, 0, 0);
}

// ---------------- fp32 -> bf16 convert (n multiple of 1024) ----------------
__global__ __launch_bounds__(256) void cvt_bf16(const float* __restrict__ in,
                                                u16* __restrict__ out) {
    int i = (blockIdx.x * 256 + threadIdx.x) * 4;
    float4 v = *(const float4*)(in + i);
    u16x4 o;
    o[0] = f2bf(v.x); o[1] = f2bf(v.y); o[2] = f2bf(v.z); o[3] = f2bf(v.w);
    *(u16x4*)(out + i) = o;
}

// ------------- deep-pipelined bf16 GEMM: C[M][N] = A[M][K] * Bt[N][K]^T -------------
// BK=64, double-buffered LDS, counted vmcnt (prefetch next tile in flight across
// compute), XOR-swizzled tiles (byte ^= (row&7)<<4) via pre-swizzled source.
// WR*WC waves; per-wave output (BM/WR) x (BN/WC).
template <int BM, int BN, int WR, int WC, bool OUT_BF16>
__global__ __launch_bounds__(WR * WC * 64, 2) void gemm_pipe(const u16* __restrict__ A,
                                                             const u16* __restrict__ Bt,
                                                             void* __restrict__ C,
                                                             int M, int N, int K) {
    constexpr int NW = WR * WC;
    constexpr int MR = BM / WR / 16, NR = BN / WC / 16;
    constexpr int CA = BM / 8, CB = BN / 8;       // 1KB staging chunks (8 rows x 128B)
    constexpr int CAW = CA / NW, CBW = CB / NW;   // chunks per wave
    constexpr int NLD = CAW + CBW;                // gloads per thread per tile

    __shared__ u16 lA[2][BM * 64];
    __shared__ u16 lB[2][BN * 64];

    const int tid = threadIdx.x, lane = tid & 63, w = tid >> 6;
    const int wr = w / WC, wc = w % WC;
    const int lr = lane & 15, lg = lane >> 4;
    const int sw = (lr & 7) << 4;                 // read-side swizzle (bytes)
    const int bm = blockIdx.x * BM, bn = blockIdx.y * BN;
    const int jr = lane >> 3;                     // row within 8-row chunk
    const int scbe = ((((lane & 7) * 16) ^ (jr << 4)) >> 1); // pre-swizzled src col (elems)
    const int nTk = K >> 6;

    f32x4 acc[MR][NR];
#pragma unroll
    for (int i = 0; i < MR; i++)
#pragma unroll
        for (int j = 0; j < NR; j++) acc[i][j] = (f32x4){0.f, 0.f, 0.f, 0.f};

    const u16* aSrc = A + (size_t)bm * K + scbe;
    const u16* bSrc = Bt + (size_t)bn * K + scbe;

#define STAGEP(p_, t_)                                                           \
    {                                                                            \
        _Pragma("unroll") for (int q = 0; q < CAW; q++) {                        \
            int ck = w * CAW + q;                                                \
            gload16(aSrc + (size_t)(ck * 8 + jr) * K + (t_) * 64,                \
                    &lA[p_][ck * 512]);                                          \
        }                                                                        \
        _Pragma("unroll") for (int q = 0; q < CBW; q++) {                        \
            int ck = w * CBW + q;                                                \
            gload16(bSrc + (size_t)(ck * 8 + jr) * K + (t_) * 64,                \
                    &lB[p_][ck * 512]);                                          \
        }                                                                        \
    }

    STAGEP(0, 0);

    for (int t = 0; t < nTk; t++) {
        const int p = t & 1;
        if (t + 1 < nTk) {
            STAGEP(p ^ 1, t + 1);
            if constexpr (NLD == 8)
                asm volatile("s_waitcnt vmcnt(8)" ::: "memory");
            else if constexpr (NLD == 7)
                asm volatile("s_waitcnt vmcnt(7)" ::: "memory");
            else
                asm volatile("s_waitcnt vmcnt(0)" ::: "memory");
        } else {
            asm volatile("s_waitcnt vmcnt(0)" ::: "memory");
        }
        __builtin_amdgcn_s_barrier();
        __builtin_amdgcn_sched_barrier(0);

        const char* pa = (const char*)&lA[p][0] + (size_t)(wr * MR * 16) * 128;
        const char* pb = (const char*)&lB[p][0] + (size_t)(wc * NR * 16) * 128;
#pragma unroll
        for (int ks = 0; ks < 2; ks++) {
            bf16x8 bfr[NR];
#pragma unroll
            for (int j = 0; j < NR; j++)
                bfr[j] = *(const bf16x8*)(pb + (j * 16 + lr) * 128 +
                                          ((ks * 64 + lg * 16) ^ sw));
#pragma unroll
            for (int mg = 0; mg < MR; mg += 4) {
                bf16x8 af[4];
#pragma unroll
                for (int i = 0; i < 4; i++)
                    af[i] = *(const bf16x8*)(pa + ((mg + i) * 16 + lr) * 128 +
                                             ((ks * 64 + lg * 16) ^ sw));
                __builtin_amdgcn_s_setprio(1);
#pragma unroll
                for (int i = 0; i < 4; i++)
#pragma unroll
                    for (int j = 0; j < NR; j++)
                        acc[mg + i][j] = __builtin_amdgcn_mfma_f32_16x16x32_bf16(
                            af[i], bfr[j], acc[mg + i][j], 0, 0, 0);
                __builtin_amdgcn_s_setprio(0);
                __builtin_amdgcn_sched_barrier(0);
            }
        }
        __builtin_amdgcn_s_barrier();
    }
#undef STAGEP

    const int row0 = bm + wr * MR * 16, col0 = bn + wc * NR * 16;
#pragma unroll
    for (int i = 0; i < MR; i++)
#pragma unroll
        for (int j = 0; j < NR; j++)
#pragma unroll
            for (int r = 0; r < 4; r++) {
                int m = row0 + i * 16 + lg * 4 + r;
                int n = col0 + j * 16 + lr;
                float v = acc[i][j][r];
                if (OUT_BF16)
                    ((u16*)C)[(size_t)m * N + n] = f2bf(v);
                else
                    ((float*)C)[(size_t)m * N + n] = v;
            }
}

// ---------------- RoPE + RMSNorm on q,k in place (bf16 qkv) ----------------
__global__ __launch_bounds__(256) void rope_rms(u16* __restrict__ qkv,
                                                const float* __restrict__ cosc,
                                                const float* __restrict__ sinc,
                                                const int* __restrict__ pos_ids) {
    int idx = blockIdx.x * 4 + (threadIdx.x >> 6);
    int lane = threadIdx.x & 63;
    int token = idx >> 5;
    int rem = idx & 31;
    int which = rem >> 4;   // 0=q, 1=k
    int h = rem & 15;
    u16* p = qkv + (size_t)token * 3072 + which * 1024 + h * 64;
    float x = bf2f(p[lane]);
    float xp = __shfl_xor(x, 32);
    int pos = pos_ids[token];
    int j = lane & 31;
    float c = cosc[pos * 32 + j], s = sinc[pos * 32 + j];
    float y = (lane < 32) ? (x * c + xp * s) : (x * c - xp * s);
    float ss = y * y;
#pragma unroll
    for (int m = 1; m < 64; m <<= 1) ss += __shfl_xor(ss, m);
    float r = rsqrtf(ss * (1.0f / 64.0f) + 1.1920929e-07f);
    p[lane] = f2bf(y * r);
}

// ---------------- transpose V: vT[bh][d=64][S] ----------------
__global__ __launch_bounds__(256) void transpose_v(const u16* __restrict__ qkv,
                                                   u16* __restrict__ vT, int S) {
    int bh = blockIdx.x;
    int b = bh >> 4, h = bh & 15;
    int s0 = blockIdx.y * 64;
    __shared__ u16 lt[64][72];
    int tid = threadIdx.x;
    {
        int s = tid >> 2, dp = (tid & 3) * 16;
        const u16* src = qkv + (size_t)(b * S + s0 + s) * 3072 + 2048 + h * 64 + dp;
        u16x8 v0 = *(const u16x8*)src;
        u16x8 v1 = *(const u16x8*)(src + 8);
#pragma unroll
        for (int i = 0; i < 8; i++) lt[s][dp + i] = v0[i];
#pragma unroll
        for (int i = 0; i < 8; i++) lt[s][dp + 8 + i] = v1[i];
    }
    __syncthreads();
    {
        int d = tid >> 2, sp = (tid & 3) * 16;
        u16x8 o0, o1;
#pragma unroll
        for (int i = 0; i < 8; i++) o0[i] = lt[sp + i][d];
#pragma unroll
        for (int i = 0; i < 8; i++) o1[i] = lt[sp + 8 + i][d];
        u16* dst = vT + ((size_t)bh * 64 + d) * S + s0 + sp;
        *(u16x8*)dst = o0;
        *(u16x8*)(dst + 8) = o1;
    }
}

// ---------------- causal flash attention, balanced-pair + dbuf ----------------
__global__ __launch_bounds__(256) void attn_fwd(const u16* __restrict__ qkv,
                                                const u16* __restrict__ vT,
                                                u16* __restrict__ out, int S) {
    const int bh = blockIdx.x, b = bh >> 4, h = bh & 15;
    const int tid = threadIdx.x, lane = tid & 63, w = tid >> 6;
    const int lr = lane & 15, lg = lane >> 4;
    const int sw = (lr & 7) << 4;            // read-side XOR swizzle (byte)

    const int nq = S >> 6;
    const int i1 = blockIdx.y;               // light tile
    const int i2 = (nq - 1) - i1;            // heavy tile
    const int n1 = i1 + 1, ntot = n1 + i2 + 1;

    __shared__ u16 lK[2][64 * 64];           // [kv][d], rows 128B, swizzled
    __shared__ u16 lVt[2][64 * 64];          // [d][kv], rows 128B, swizzled
    __shared__ u16 lP[4][16 * 64];           // per wave: P[q][k], swizzled

    const int jr = lane >> 3;                // row within chunk
    const int cbyte = (lane & 7) * 16;
    const int scb = cbyte ^ (jr << 4);       // pre-swizzled source byte col
    const int rowA = w * 16 + jr, rowB = rowA + 8;
    const u16* kSrc = qkv + 1024 + h * 64 + (scb >> 1);
    const u16* vSrc = vT + (size_t)bh * 64 * S + (scb >> 1);

#define STAGE(bufi, kv0_)                                                        \
    {                                                                            \
        const u16* kb = kSrc + (size_t)(b * S + (kv0_)) * 3072;                  \
        const u16* vb = vSrc + (kv0_);                                           \
        gload16(kb + (size_t)rowA * 3072, &lK[bufi][(w * 2) * 512]);             \
        gload16(kb + (size_t)rowB * 3072, &lK[bufi][(w * 2 + 1) * 512]);         \
        gload16(vb + (size_t)rowA * S, &lVt[bufi][(w * 2) * 512]);               \
        gload16(vb + (size_t)rowB * S, &lVt[bufi][(w * 2 + 1) * 512]);           \
    }

    bf16x8 bQ[2];
    f32x4 oT[4];
    float mrun, lrun;

#define LOADQ(tile_)                                                             \
    {                                                                            \
        const u16* qp = qkv + (size_t)(b * S + (tile_)*64 + w * 16 + lr) * 3072 + h * 64; \
        _Pragma("unroll") for (int hf = 0; hf < 2; hf++) {                       \
            u16x8 t = *(const u16x8*)(qp + hf * 32 + lg * 8);                    \
            bf16x8 a;                                                            \
            _Pragma("unroll") for (int i = 0; i < 8; i++)                        \
                a[i] = (__bf16)(bf2f(t[i]) * 0.125f);                            \
            bQ[hf] = a;                                                          \
        }                                                                        \
    }

    STAGE(0, 0);
    LOADQ(i1);
#pragma unroll
    for (int df = 0; df < 4; df++) oT[df] = (f32x4){0.f, 0.f, 0.f, 0.f};
    mrun = -3.0e38f; lrun = 0.f;
    __syncthreads();

    int buf = 0;
    for (int s = 0; s < ntot; s++) {
        const int tile = (s < n1) ? i1 : i2;
        const int kv0 = ((s < n1) ? s : s - n1) * 64;
        if (s + 1 < ntot) {
            int ns = s + 1;
            int nkv0 = ((ns < n1) ? ns : ns - n1) * 64;
            STAGE(buf ^ 1, nkv0);
        }
        const bool diag = (s == n1 - 1) || (s == ntot - 1);

        // ---- QK^T (swapped): S^T[kv][q] ----
        f32x4 st[4];
#pragma unroll
        for (int kf = 0; kf < 4; kf++) {
            const char* kb = (const char*)&lK[buf][0] + (kf * 16 + lr) * 128;
            bf16x8 k0 = *(const bf16x8*)(kb + ((lg * 16) ^ sw));
            bf16x8 k1 = *(const bf16x8*)(kb + ((64 + lg * 16) ^ sw));
            f32x4 z = (f32x4){0.f, 0.f, 0.f, 0.f};
            z = __builtin_amdgcn_mfma_f32_16x16x32_bf16(k0, bQ[0], z, 0, 0, 0);
            st[kf] = __builtin_amdgcn_mfma_f32_16x16x32_bf16(k1, bQ[1], z, 0, 0, 0);
        }

        // ---- mask (diagonal steps only) + lane-local online softmax ----
        if (diag) {
            const int qg = tile * 64 + w * 16 + lr;
#pragma unroll
            for (int kf = 0; kf < 4; kf++)
#pragma unroll
                for (int r = 0; r < 4; r++) {
                    int kvg = kv0 + kf * 16 + lg * 4 + r;
                    if (kvg > qg) st[kf][r] = -3.0e38f;
                }
        }
        float mx = -3.0e38f;
#pragma unroll
        for (int kf = 0; kf < 4; kf++) {
            float m01 = fmaxf(st[kf][0], st[kf][1]);
            float m23 = fmaxf(st[kf][2], st[kf][3]);
            mx = fmaxf(mx, fmaxf(m01, m23));
        }
        mx = fmaxf(mx, __shfl_xor(mx, 16));
        mx = fmaxf(mx, __shfl_xor(mx, 32));
        if (!__all(mx <= mrun + 8.f)) {       // T13 defer-max
            float mnew = fmaxf(mrun, mx);
            float alpha = __expf(mrun - mnew);
            mrun = mnew;
            lrun *= alpha;
#pragma unroll
            for (int df = 0; df < 4; df++)
#pragma unroll
                for (int r = 0; r < 4; r++) oT[df][r] *= alpha;
        }
        float ps = 0.f;
#pragma unroll
        for (int kf = 0; kf < 4; kf++)
#pragma unroll
            for (int r = 0; r < 4; r++) {
                float p = __expf(st[kf][r] - mrun);
                st[kf][r] = p;
                ps += p;
            }
        ps += __shfl_xor(ps, 16);
        ps += __shfl_xor(ps, 32);
        lrun += ps;

        // ---- P -> LDS (bf16, swizzled rows of 128B) ----
        {
            char* pb = (char*)&lP[w][0] + lr * 128;
#pragma unroll
            for (int kf = 0; kf < 4; kf++) {
                uint2 pk;
                pk.x = cvt_pk_bf16(st[kf][0], st[kf][1]);
                pk.y = cvt_pk_bf16(st[kf][2], st[kf][3]);
                *(uint2*)(pb + ((kf * 32 + lg * 8) ^ sw)) = pk;
            }
        }

        // ---- PV (swapped): O^T += Vt . P^T ----
#pragma unroll
        for (int kc = 0; kc < 2; kc++) {
            bf16x8 bp = *(const bf16x8*)((const char*)&lP[w][0] + lr * 128 +
                                         ((kc * 64 + lg * 16) ^ sw));
#pragma unroll
            for (int df = 0; df < 4; df++) {
                bf16x8 av = *(const bf16x8*)((const char*)&lVt[buf][0] +
                                             (df * 16 + lr) * 128 +
                                             ((kc * 64 + lg * 16) ^ sw));
                oT[df] = __builtin_amdgcn_mfma_f32_16x16x32_bf16(av, bp, oT[df], 0, 0, 0);
            }
        }

        if (diag) {
            float inv = 1.0f / lrun;
            u16* op = out + (size_t)(b * S + tile * 64 + w * 16 + lr) * 1024 +
                      h * 64 + lg * 4;
#pragma unroll
            for (int df = 0; df < 4; df++) {
                u16x4 o;
#pragma unroll
                for (int r = 0; r < 4; r++) o[r] = f2bf(oT[df][r] * inv);
                *(u16x4*)(op + df * 16) = o;
            }
            if (s != ntot - 1) {              // switch to heavy tile
                LOADQ(i2);
#pragma unroll
                for (int df = 0; df < 4; df++) oT[df] = (f32x4){0.f, 0.f, 0.f, 0.f};
                mrun = -3.0e38f; lrun = 0.f;
            }
        }
        __syncthreads();
        buf ^= 1;
    }
#undef STAGE
#undef LOADQ
}

extern "C" void kernel_launch(void* const* d_in, const int* in_sizes, int n_in,
                              void* d_out, int out_size, void* d_ws, size_t ws_size,
                              hipStream_t stream) {
    const float* x     = (const float*)d_in[0];
    const float* Wqkv  = (const float*)d_in[1];
    const float* Wo    = (const float*)d_in[2];
    const float* cosc  = (const float*)d_in[3];
    const float* sinc  = (const float*)d_in[4];
    const int* pos_ids = (const int*)d_in[6];

    const int E = 1024, H = 16;
    int S = in_sizes[3] / 32;       // cos_cache is S x 32
    int N = in_sizes[0] / E;
    int B = N / S;

    char* ws = (char*)d_ws;
    u16* xb    = (u16*)ws;                                          // N*E bf16 (reused as attn out)
    u16* wqkvb = (u16*)(ws + (size_t)N * E * 2);                    // 3E*E
    u16* wob   = (u16*)(ws + (size_t)N * E * 2 + (size_t)3 * E * E * 2);
    u16* qkvb  = (u16*)(ws + (size_t)N * E * 2 + (size_t)4 * E * E * 2);
    u16* vTb   = (u16*)(ws + (size_t)N * E * 2 + (size_t)4 * E * E * 2 + (size_t)N * 3 * E * 2);
    u16* aout  = xb;

    cvt_bf16<<<(size_t)N * E / 1024, 256, 0, stream>>>(x, xb);
    cvt_bf16<<<(size_t)3 * E * E / 1024, 256, 0, stream>>>(Wqkv, wqkvb);
    cvt_bf16<<<(size_t)E * E / 1024, 256, 0, stream>>>(Wo, wob);

    // qkv GEMM: 256x192 tiles -> grid 16x16 = 256 blocks (exact CU fill)
    gemm_pipe<256, 192, 2, 4, true><<<dim3(N / 256, 3 * E / 192), 512, 0, stream>>>(
        xb, wqkvb, qkvb, N, 3 * E, E);

    rope_rms<<<N * 2 * H / 4, 256, 0, stream>>>(qkvb, cosc, sinc, pos_ids);

    transpose_v<<<dim3(B * H, S / 64), 256, 0, stream>>>(qkvb, vTb, S);

    attn_fwd<<<dim3(B * H, S / 128), 256, 0, stream>>>(qkvb, vTb, aout, S);

    // out GEMM: 128x128 tiles -> grid 32x8 = 256 blocks
    gemm_pipe<128, 128, 2, 2, false><<<dim3(N / 128, E / 128), 256, 0, stream>>>(
        aout, wob, d_out, N, E, E);
}

// Round 5
// 115.214 us; speedup vs baseline: 1.4448x; 1.0475x over previous
//
#include <hip/hip_runtime.h>
#include <hip/hip_bf16.h>

typedef unsigned short u16;
typedef __bf16 bf16x8 __attribute__((ext_vector_type(8)));
typedef float f32x4 __attribute__((ext_vector_type(4)));
typedef u16 u16x8 __attribute__((ext_vector_type(8)));
typedef u16 u16x4 __attribute__((ext_vector_type(4)));

__device__ __forceinline__ u16 f2bf(float f) {
    unsigned u = __builtin_bit_cast(unsigned, f);
    unsigned r = u + 0x7FFFu + ((u >> 16) & 1u);
    return (u16)(r >> 16);
}
__device__ __forceinline__ float bf2f(u16 h) {
    return __builtin_bit_cast(float, (unsigned)h << 16);
}
__device__ __forceinline__ unsigned cvt_pk_bf16(float lo, float hi) {
    unsigned r;
    asm("v_cvt_pk_bf16_f32 %0, %1, %2" : "=v"(r) : "v"(lo), "v"(hi));
    return r;
}
__device__ __forceinline__ void gload16(const void* g, void* l) {
    __builtin_amdgcn_global_load_lds((const __attribute__((address_space(1))) void*)g,
                                     (__attribute__((address_space(3))) void*)l, 16, 0, 0);
}

// ---------- fused fp32 -> bf16 convert of x | Wqkv | Wo into contiguous ws ----------
__global__ __launch_bounds__(256) void cvt_all(const float* __restrict__ x,
                                               const float* __restrict__ wqkv,
                                               const float* __restrict__ wo,
                                               u16* __restrict__ dst, int n0, int n1) {
    int i = (blockIdx.x * 256 + threadIdx.x) * 4;
    const float* src;
    if (i < n0)            src = x + i;
    else if (i < n0 + n1)  src = wqkv + (i - n0);
    else                   src = wo + (i - n0 - n1);
    float4 v = *(const float4*)src;
    u16x4 o;
    o[0] = f2bf(v.x); o[1] = f2bf(v.y); o[2] = f2bf(v.z); o[3] = f2bf(v.w);
    *(u16x4*)(dst + i) = o;
}

// ------------- deep-pipelined bf16 GEMM: C[M][N] = A[M][K] * Bt[N][K]^T -------------
// BK=64, double-buffered LDS, counted vmcnt (prefetch next tile in flight across
// compute), XOR-swizzled tiles (byte ^= (row&7)<<4) via pre-swizzled source.
// No mid-loop sched_barrier pins (m141): compiler interleaves ds_read with MFMA.
template <int BM, int BN, int WR, int WC, bool OUT_BF16>
__global__ __launch_bounds__(WR * WC * 64, 2) void gemm_pipe(const u16* __restrict__ A,
                                                             const u16* __restrict__ Bt,
                                                             void* __restrict__ C,
                                                             int M, int N, int K) {
    constexpr int NW = WR * WC;
    constexpr int MR = BM / WR / 16, NR = BN / WC / 16;
    constexpr int CA = BM / 8, CB = BN / 8;       // 1KB staging chunks (8 rows x 128B)
    constexpr int CAW = CA / NW, CBW = CB / NW;   // chunks per wave
    constexpr int NLD = CAW + CBW;                // gloads per thread per tile

    __shared__ u16 lA[2][BM * 64];
    __shared__ u16 lB[2][BN * 64];

    const int tid = threadIdx.x, lane = tid & 63, w = tid >> 6;
    const int wr = w / WC, wc = w % WC;
    const int lr = lane & 15, lg = lane >> 4;
    const int sw = (lr & 7) << 4;                 // read-side swizzle (bytes)
    const int bm = blockIdx.x * BM, bn = blockIdx.y * BN;
    const int jr = lane >> 3;                     // row within 8-row chunk
    const int scbe = ((((lane & 7) * 16) ^ (jr << 4)) >> 1); // pre-swizzled src col (elems)
    const int nTk = K >> 6;

    f32x4 acc[MR][NR];
#pragma unroll
    for (int i = 0; i < MR; i++)
#pragma unroll
        for (int j = 0; j < NR; j++) acc[i][j] = (f32x4){0.f, 0.f, 0.f, 0.f};

    const u16* aSrc = A + (size_t)bm * K + scbe;
    const u16* bSrc = Bt + (size_t)bn * K + scbe;

#define STAGEP(p_, t_)                                                           \
    {                                                                            \
        _Pragma("unroll") for (int q = 0; q < CAW; q++) {                        \
            int ck = w * CAW + q;                                                \
            gload16(aSrc + (size_t)(ck * 8 + jr) * K + (t_) * 64,                \
                    &lA[p_][ck * 512]);                                          \
        }                                                                        \
        _Pragma("unroll") for (int q = 0; q < CBW; q++) {                        \
            int ck = w * CBW + q;                                                \
            gload16(bSrc + (size_t)(ck * 8 + jr) * K + (t_) * 64,                \
                    &lB[p_][ck * 512]);                                          \
        }                                                                        \
    }

    STAGEP(0, 0);

    for (int t = 0; t < nTk; t++) {
        const int p = t & 1;
        if (t + 1 < nTk) {
            STAGEP(p ^ 1, t + 1);
            if constexpr (NLD == 8)
                asm volatile("s_waitcnt vmcnt(8)" ::: "memory");
            else if constexpr (NLD == 7)
                asm volatile("s_waitcnt vmcnt(7)" ::: "memory");
            else
                asm volatile("s_waitcnt vmcnt(0)" ::: "memory");
        } else {
            asm volatile("s_waitcnt vmcnt(0)" ::: "memory");
        }
        __builtin_amdgcn_s_barrier();
        __builtin_amdgcn_sched_barrier(0);        // keep ds_reads below the barrier

        const char* pa = (const char*)&lA[p][0] + (size_t)(wr * MR * 16) * 128;
        const char* pb = (const char*)&lB[p][0] + (size_t)(wc * NR * 16) * 128;
#pragma unroll
        for (int ks = 0; ks < 2; ks++) {
            bf16x8 bfr[NR];
#pragma unroll
            for (int j = 0; j < NR; j++)
                bfr[j] = *(const bf16x8*)(pb + (j * 16 + lr) * 128 +
                                          ((ks * 64 + lg * 16) ^ sw));
#pragma unroll
            for (int mg = 0; mg < MR; mg += 4) {
                bf16x8 af[4];
#pragma unroll
                for (int i = 0; i < 4; i++)
                    af[i] = *(const bf16x8*)(pa + ((mg + i) * 16 + lr) * 128 +
                                             ((ks * 64 + lg * 16) ^ sw));
                __builtin_amdgcn_s_setprio(1);
#pragma unroll
                for (int i = 0; i < 4; i++)
#pragma unroll
                    for (int j = 0; j < NR; j++)
                        acc[mg + i][j] = __builtin_amdgcn_mfma_f32_16x16x32_bf16(
                            af[i], bfr[j], acc[mg + i][j], 0, 0, 0);
                __builtin_amdgcn_s_setprio(0);
            }
        }
        __builtin_amdgcn_s_barrier();
    }
#undef STAGEP

    const int row0 = bm + wr * MR * 16, col0 = bn + wc * NR * 16;
#pragma unroll
    for (int i = 0; i < MR; i++)
#pragma unroll
        for (int j = 0; j < NR; j++)
#pragma unroll
            for (int r = 0; r < 4; r++) {
                int m = row0 + i * 16 + lg * 4 + r;
                int n = col0 + j * 16 + lr;
                float v = acc[i][j][r];
                if (OUT_BF16)
                    ((u16*)C)[(size_t)m * N + n] = f2bf(v);
                else
                    ((float*)C)[(size_t)m * N + n] = v;
            }
}

// ---------- fused RoPE+RMSNorm (blocks [0,nbRope)) + V transpose (rest) ----------
__global__ __launch_bounds__(256) void rope_trans(u16* __restrict__ qkv,
                                                  const float* __restrict__ cosc,
                                                  const float* __restrict__ sinc,
                                                  const int* __restrict__ pos_ids,
                                                  u16* __restrict__ vT, int S, int nbRope) {
    __shared__ u16 lt[64][72];
    const int bid = blockIdx.x;
    const int tid = threadIdx.x;
    if (bid < nbRope) {
        int idx = bid * 4 + (tid >> 6);
        int lane = tid & 63;
        int token = idx >> 5;
        int rem = idx & 31;
        int which = rem >> 4;   // 0=q, 1=k
        int h = rem & 15;
        u16* p = qkv + (size_t)token * 3072 + which * 1024 + h * 64;
        float x = bf2f(p[lane]);
        float xp = __shfl_xor(x, 32);
        int pos = pos_ids[token];
        int j = lane & 31;
        float c = cosc[pos * 32 + j], s = sinc[pos * 32 + j];
        float y = (lane < 32) ? (x * c + xp * s) : (x * c - xp * s);
        float ss = y * y;
#pragma unroll
        for (int m = 1; m < 64; m <<= 1) ss += __shfl_xor(ss, m);
        float r = rsqrtf(ss * (1.0f / 64.0f) + 1.1920929e-07f);
        p[lane] = f2bf(y * r);
    } else {
        int t = bid - nbRope;
        int nsc = S >> 6;
        int bh = t / nsc;
        int b = bh >> 4, h = bh & 15;
        int s0 = (t - bh * nsc) * 64;
        {
            int s = tid >> 2, dp = (tid & 3) * 16;
            const u16* src = qkv + (size_t)(b * S + s0 + s) * 3072 + 2048 + h * 64 + dp;
            u16x8 v0 = *(const u16x8*)src;
            u16x8 v1 = *(const u16x8*)(src + 8);
#pragma unroll
            for (int i = 0; i < 8; i++) lt[s][dp + i] = v0[i];
#pragma unroll
            for (int i = 0; i < 8; i++) lt[s][dp + 8 + i] = v1[i];
        }
        __syncthreads();
        {
            int d = tid >> 2, sp = (tid & 3) * 16;
            u16x8 o0, o1;
#pragma unroll
            for (int i = 0; i < 8; i++) o0[i] = lt[sp + i][d];
#pragma unroll
            for (int i = 0; i < 8; i++) o1[i] = lt[sp + 8 + i][d];
            u16* dst = vT + ((size_t)bh * 64 + d) * S + s0 + sp;
            *(u16x8*)dst = o0;
            *(u16x8*)(dst + 8) = o1;
        }
    }
}

// ---------------- causal flash attention, balanced-pair + dbuf ----------------
__global__ __launch_bounds__(256) void attn_fwd(const u16* __restrict__ qkv,
                                                const u16* __restrict__ vT,
                                                u16* __restrict__ out, int S) {
    const int bh = blockIdx.x, b = bh >> 4, h = bh & 15;
    const int tid = threadIdx.x, lane = tid & 63, w = tid >> 6;
    const int lr = lane & 15, lg = lane >> 4;
    const int sw = (lr & 7) << 4;            // read-side XOR swizzle (byte)

    const int nq = S >> 6;
    const int i1 = blockIdx.y;               // light tile
    const int i2 = (nq - 1) - i1;            // heavy tile
    const int n1 = i1 + 1, ntot = n1 + i2 + 1;

    __shared__ u16 lK[2][64 * 64];           // [kv][d], rows 128B, swizzled
    __shared__ u16 lVt[2][64 * 64];          // [d][kv], rows 128B, swizzled
    __shared__ u16 lP[4][16 * 64];           // per wave: P[q][k], swizzled

    const int jr = lane >> 3;                // row within chunk
    const int cbyte = (lane & 7) * 16;
    const int scb = cbyte ^ (jr << 4);       // pre-swizzled source byte col
    const int rowA = w * 16 + jr, rowB = rowA + 8;
    const u16* kSrc = qkv + 1024 + h * 64 + (scb >> 1);
    const u16* vSrc = vT + (size_t)bh * 64 * S + (scb >> 1);

#define STAGE(bufi, kv0_)                                                        \
    {                                                                            \
        const u16* kb = kSrc + (size_t)(b * S + (kv0_)) * 3072;                  \
        const u16* vb = vSrc + (kv0_);                                           \
        gload16(kb + (size_t)rowA * 3072, &lK[bufi][(w * 2) * 512]);             \
        gload16(kb + (size_t)rowB * 3072, &lK[bufi][(w * 2 + 1) * 512]);         \
        gload16(vb + (size_t)rowA * S, &lVt[bufi][(w * 2) * 512]);               \
        gload16(vb + (size_t)rowB * S, &lVt[bufi][(w * 2 + 1) * 512]);           \
    }

    bf16x8 bQ[2];
    f32x4 oT[4];
    float mrun, lrun;

#define LOADQ(tile_)                                                             \
    {                                                                            \
        const u16* qp = qkv + (size_t)(b * S + (tile_)*64 + w * 16 + lr) * 3072 + h * 64; \
        _Pragma("unroll") for (int hf = 0; hf < 2; hf++) {                       \
            u16x8 t = *(const u16x8*)(qp + hf * 32 + lg * 8);                    \
            bf16x8 a;                                                            \
            _Pragma("unroll") for (int i = 0; i < 8; i++)                        \
                a[i] = (__bf16)(bf2f(t[i]) * 0.125f);                            \
            bQ[hf] = a;                                                          \
        }                                                                        \
    }

    STAGE(0, 0);
    LOADQ(i1);
#pragma unroll
    for (int df = 0; df < 4; df++) oT[df] = (f32x4){0.f, 0.f, 0.f, 0.f};
    mrun = -3.0e38f; lrun = 0.f;
    __syncthreads();

    int buf = 0;
    for (int s = 0; s < ntot; s++) {
        const int tile = (s < n1) ? i1 : i2;
        const int kv0 = ((s < n1) ? s : s - n1) * 64;
        if (s + 1 < ntot) {
            int ns = s + 1;
            int nkv0 = ((ns < n1) ? ns : ns - n1) * 64;
            STAGE(buf ^ 1, nkv0);
        }
        const bool diag = (s == n1 - 1) || (s == ntot - 1);

        // ---- QK^T (swapped): S^T[kv][q] ----
        f32x4 st[4];
#pragma unroll
        for (int kf = 0; kf < 4; kf++) {
            const char* kb = (const char*)&lK[buf][0] + (kf * 16 + lr) * 128;
            bf16x8 k0 = *(const bf16x8*)(kb + ((lg * 16) ^ sw));
            bf16x8 k1 = *(const bf16x8*)(kb + ((64 + lg * 16) ^ sw));
            f32x4 z = (f32x4){0.f, 0.f, 0.f, 0.f};
            z = __builtin_amdgcn_mfma_f32_16x16x32_bf16(k0, bQ[0], z, 0, 0, 0);
            st[kf] = __builtin_amdgcn_mfma_f32_16x16x32_bf16(k1, bQ[1], z, 0, 0, 0);
        }

        // ---- mask (diagonal steps only) + lane-local online softmax ----
        if (diag) {
            const int qg = tile * 64 + w * 16 + lr;
#pragma unroll
            for (int kf = 0; kf < 4; kf++)
#pragma unroll
                for (int r = 0; r < 4; r++) {
                    int kvg = kv0 + kf * 16 + lg * 4 + r;
                    if (kvg > qg) st[kf][r] = -3.0e38f;
                }
        }
        float mx = -3.0e38f;
#pragma unroll
        for (int kf = 0; kf < 4; kf++) {
            float m01 = fmaxf(st[kf][0], st[kf][1]);
            float m23 = fmaxf(st[kf][2], st[kf][3]);
            mx = fmaxf(mx, fmaxf(m01, m23));
        }
        mx = fmaxf(mx, __shfl_xor(mx, 16));
        mx = fmaxf(mx, __shfl_xor(mx, 32));
        if (!__all(mx <= mrun + 8.f)) {       // T13 defer-max
            float mnew = fmaxf(mrun, mx);
            float alpha = __expf(mrun - mnew);
            mrun = mnew;
            lrun *= alpha;
#pragma unroll
            for (int df = 0; df < 4; df++)
#pragma unroll
                for (int r = 0; r < 4; r++) oT[df][r] *= alpha;
        }
        float ps = 0.f;
#pragma unroll
        for (int kf = 0; kf < 4; kf++)
#pragma unroll
            for (int r = 0; r < 4; r++) {
                float p = __expf(st[kf][r] - mrun);
                st[kf][r] = p;
                ps += p;
            }
        ps += __shfl_xor(ps, 16);
        ps += __shfl_xor(ps, 32);
        lrun += ps;

        // ---- P -> LDS (bf16, swizzled rows of 128B) ----
        {
            char* pb = (char*)&lP[w][0] + lr * 128;
#pragma unroll
            for (int kf = 0; kf < 4; kf++) {
                uint2 pk;
                pk.x = cvt_pk_bf16(st[kf][0], st[kf][1]);
                pk.y = cvt_pk_bf16(st[kf][2], st[kf][3]);
                *(uint2*)(pb + ((kf * 32 + lg * 8) ^ sw)) = pk;
            }
        }

        // ---- PV (swapped): O^T += Vt . P^T ----
#pragma unroll
        for (int kc = 0; kc < 2; kc++) {
            bf16x8 bp = *(const bf16x8*)((const char*)&lP[w][0] + lr * 128 +
                                         ((kc * 64 + lg * 16) ^ sw));
#pragma unroll
            for (int df = 0; df < 4; df++) {
                bf16x8 av = *(const bf16x8*)((const char*)&lVt[buf][0] +
                                             (df * 16 + lr) * 128 +
                                             ((kc * 64 + lg * 16) ^ sw));
                oT[df] = __builtin_amdgcn_mfma_f32_16x16x32_bf16(av, bp, oT[df], 0, 0, 0);
            }
        }

        if (diag) {
            float inv = 1.0f / lrun;
            u16* op = out + (size_t)(b * S + tile * 64 + w * 16 + lr) * 1024 +
                      h * 64 + lg * 4;
#pragma unroll
            for (int df = 0; df < 4; df++) {
                u16x4 o;
#pragma unroll
                for (int r = 0; r < 4; r++) o[r] = f2bf(oT[df][r] * inv);
                *(u16x4*)(op + df * 16) = o;
            }
            if (s != ntot - 1) {              // switch to heavy tile
                LOADQ(i2);
#pragma unroll
                for (int df = 0; df < 4; df++) oT[df] = (f32x4){0.f, 0.f, 0.f, 0.f};
                mrun = -3.0e38f; lrun = 0.f;
            }
        }
        __syncthreads();
        buf ^= 1;
    }
#undef STAGE
#undef LOADQ
}

extern "C" void kernel_launch(void* const* d_in, const int* in_sizes, int n_in,
                              void* d_out, int out_size, void* d_ws, size_t ws_size,
                              hipStream_t stream) {
    const float* x     = (const float*)d_in[0];
    const float* Wqkv  = (const float*)d_in[1];
    const float* Wo    = (const float*)d_in[2];
    const float* cosc  = (const float*)d_in[3];
    const float* sinc  = (const float*)d_in[4];
    const int* pos_ids = (const int*)d_in[6];

    const int E = 1024, H = 16;
    int S = in_sizes[3] / 32;       // cos_cache is S x 32
    int N = in_sizes[0] / E;
    int B = N / S;

    char* ws = (char*)d_ws;
    u16* xb    = (u16*)ws;                                          // N*E bf16 (reused as attn out)
    u16* wqkvb = (u16*)(ws + (size_t)N * E * 2);                    // 3E*E
    u16* wob   = (u16*)(ws + (size_t)N * E * 2 + (size_t)3 * E * E * 2);
    u16* qkvb  = (u16*)(ws + (size_t)N * E * 2 + (size_t)4 * E * E * 2);
    u16* vTb   = (u16*)(ws + (size_t)N * E * 2 + (size_t)4 * E * E * 2 + (size_t)N * 3 * E * 2);
    u16* aout  = xb;

    // one fused convert: dest segments xb|wqkvb|wob are contiguous in ws
    int n0 = N * E, n1 = 3 * E * E, n2 = E * E;
    cvt_all<<<(n0 + n1 + n2) / 1024, 256, 0, stream>>>(x, Wqkv, Wo, xb, n0, n1);

    // qkv GEMM: 256x192 tiles -> grid 16x16 = 256 blocks (exact CU fill)
    gemm_pipe<256, 192, 2, 4, true><<<dim3(N / 256, 3 * E / 192), 512, 0, stream>>>(
        xb, wqkvb, qkvb, N, 3 * E, E);

    // fused RoPE+RMS (q,k) + V transpose
    int nbRope = N * 2 * H / 4;
    int nbTrans = B * H * (S / 64);
    rope_trans<<<nbRope + nbTrans, 256, 0, stream>>>(qkvb, cosc, sinc, pos_ids, vTb, S, nbRope);

    attn_fwd<<<dim3(B * H, S / 128), 256, 0, stream>>>(qkvb, vTb, aout, S);

    // out GEMM: 128x128 tiles -> grid 32x8 = 256 blocks
    gemm_pipe<128, 128, 2, 2, false><<<dim3(N / 128, E / 128), 256, 0, stream>>>(
        aout, wob, d_out, N, E, E);
}